// Round 2
// baseline (367.212 us; speedup 1.0000x reference)
//
#include <hip/hip_runtime.h>
#include <hip/hip_bf16.h>
#include <cstdint>
#include <cstddef>

// K(x,y) = exp(-0.5*||x-y||^2) + 0.1*(x.y^T + 1)^3
// x,y: (8192, 256) fp32. out: (8192, 8192) fp32.
//
// R1 structure: NO LDS, no barriers. Inputs (8 MB bf16 total) are L2/L3
// resident, so MFMA fragments are loaded DIRECTLY global->VGPR:
//   lane reads x[row + l15][kt + quad*8 .. +7] as one 16-B dwordx4;
//   lanes {r, r+16, r+32, r+48} cover 64 contiguous bytes of one row.
// The compiler software-pipelines the fully-unrolled 8 K-tiles with counted
// vmcnt — no vmcnt(0)/lgkmcnt(0) barrier drains (the R0 bottleneck).
// XCD swizzle: each XCD gets a 32(bm) x 16(bn) rectangle of the block grid
// -> per-XCD L2 working set = 2 MB (A) + 1 MB (B) < 4 MB.

#define NROWS 8192
#define DK    256
#define BM    128
#define BN    128

typedef __bf16 bf16_8 __attribute__((ext_vector_type(8)));
typedef float  f32x4  __attribute__((ext_vector_type(4)));

__device__ __forceinline__ unsigned short f2bf(float f) {
    unsigned int u = __builtin_bit_cast(unsigned int, f);
    u = (u + 0x7FFFu + ((u >> 16) & 1u)) >> 16;  // round-to-nearest-even
    return (unsigned short)u;
}

// ---------------------------------------------------------------------------
// Prep: fp32 -> bf16 conversion + row squared-norms (fp32, exact-ish).
// One wave per row pair (x row b, y row b). 8192 blocks x 64 threads.
// ---------------------------------------------------------------------------
__global__ __launch_bounds__(64) void prep_kernel(
    const float* __restrict__ x, const float* __restrict__ y,
    unsigned short* __restrict__ xb, unsigned short* __restrict__ yb,
    float* __restrict__ x2, float* __restrict__ y2)
{
    const int row  = blockIdx.x;
    const int lane = threadIdx.x;          // 0..63, 4 floats each = 256
    const size_t base = (size_t)row * DK + lane * 4;

    const float4 vx = *(const float4*)(x + base);
    const float4 vy = *(const float4*)(y + base);

    ushort4 hx = make_ushort4(f2bf(vx.x), f2bf(vx.y), f2bf(vx.z), f2bf(vx.w));
    ushort4 hy = make_ushort4(f2bf(vy.x), f2bf(vy.y), f2bf(vy.z), f2bf(vy.w));
    *(ushort4*)(xb + base) = hx;
    *(ushort4*)(yb + base) = hy;

    float sx = vx.x * vx.x + vx.y * vx.y + vx.z * vx.z + vx.w * vx.w;
    float sy = vy.x * vy.x + vy.y * vy.y + vy.z * vy.z + vy.w * vy.w;
    #pragma unroll
    for (int off = 32; off > 0; off >>= 1) {
        sx += __shfl_down(sx, off);
        sy += __shfl_down(sy, off);
    }
    if (lane == 0) {
        x2[row] = sx;
        y2[row] = sy;
    }
}

// ---------------------------------------------------------------------------
// GEMM + fused epilogue. C = x_bf @ y_bf^T with 16x16x32 bf16 MFMA.
// Block = 256 threads = 4 waves in 2x2, each wave owns a 64x64 sub-tile
// (4x4 grid of 16x16 MFMA tiles). Fragments come straight from global (L2).
// ---------------------------------------------------------------------------
__global__ __launch_bounds__(256, 2) void gemm_ep_kernel(
    const unsigned short* __restrict__ xb, const unsigned short* __restrict__ yb,
    const float* __restrict__ x2, const float* __restrict__ y2,
    float* __restrict__ out)
{
    const int tid  = threadIdx.x;
    const int wave = tid >> 6;
    const int lane = tid & 63;

    // XCD-chunked remap: 1D grid of 4096, xcd = id%8 (HW round-robin).
    // Each XCD owns a 32(bm) x 16(bn) rectangle -> L2 working set 3 MB.
    const int id  = blockIdx.x;
    const int xcd = id & 7;
    const int idx = id >> 3;                   // 0..511
    const int bm  = (xcd & 1) * 32 + (idx & 31);
    const int bn  = (xcd >> 1) * 16 + (idx >> 5);

    const int wm = (wave & 1) * 64;   // wave's row offset in 128-tile
    const int wn = (wave >> 1) * 64;  // wave's col offset in 128-tile

    const int quad = lane >> 4;   // 0..3
    const int l15  = lane & 15;

    // Fragment base pointers: A[row][k], row = bm*BM+wm+i*16+l15,
    // k = kt + quad*8 .. +7 (16 B). K-tile offset folds into the 13-bit imm.
    const unsigned short* gA[4];
    const unsigned short* gB[4];
    #pragma unroll
    for (int i = 0; i < 4; ++i) {
        gA[i] = xb + (size_t)(bm * BM + wm + i * 16 + l15) * DK + quad * 8;
        gB[i] = yb + (size_t)(bn * BN + wn + i * 16 + l15) * DK + quad * 8;
    }

    f32x4 acc[4][4];
    #pragma unroll
    for (int i = 0; i < 4; ++i)
        #pragma unroll
        for (int j = 0; j < 4; ++j)
            acc[i][j] = (f32x4){0.f, 0.f, 0.f, 0.f};

    // 8 K-tiles of 32, fully unrolled; no barriers, compiler pipelines.
    #pragma unroll
    for (int kt = 0; kt < DK; kt += 32) {
        bf16_8 afr[4], bfr[4];
        #pragma unroll
        for (int i = 0; i < 4; ++i)
            afr[i] = *(const bf16_8*)(gA[i] + kt);
        #pragma unroll
        for (int j = 0; j < 4; ++j)
            bfr[j] = *(const bf16_8*)(gB[j] + kt);

        #pragma unroll
        for (int i = 0; i < 4; ++i)
            #pragma unroll
            for (int j = 0; j < 4; ++j)
                acc[i][j] = __builtin_amdgcn_mfma_f32_16x16x32_bf16(
                    afr[i], bfr[j], acc[i][j], 0, 0, 0);
    }

    // --- epilogue. C/D layout (verified m89/m91): col = lane&15, row = quad*4+reg
    const int mBase = bm * BM + wm + quad * 4;
    const int nBase = bn * BN + wn + l15;

    float y2v[4];
    #pragma unroll
    for (int j = 0; j < 4; ++j) y2v[j] = y2[nBase + j * 16];

    #pragma unroll
    for (int i = 0; i < 4; ++i) {
        #pragma unroll
        for (int r = 0; r < 4; ++r) {
            const int m = mBase + i * 16 + r;
            const float xv = x2[m];
            float* orow = out + (size_t)m * NROWS + nBase;
            #pragma unroll
            for (int j = 0; j < 4; ++j) {
                const float xy = acc[i][j][r];
                float s = xv + y2v[j] - 2.0f * xy;
                s = fmaxf(s, 0.0f);
                const float e = __expf(-0.5f * s);
                const float p = xy + 1.0f;
                orow[j * 16] = fmaf(0.1f, p * p * p, e);
            }
        }
    }
}

// ---------------------------------------------------------------------------
extern "C" void kernel_launch(void* const* d_in, const int* in_sizes, int n_in,
                              void* d_out, int out_size, void* d_ws, size_t ws_size,
                              hipStream_t stream) {
    const float* x = (const float*)d_in[0];
    const float* y = (const float*)d_in[1];
    float* out = (float*)d_out;

    char* ws = (char*)d_ws;
    unsigned short* xb = (unsigned short*)ws;                                  // 4 MB
    unsigned short* yb = (unsigned short*)(ws + (size_t)NROWS * DK * 2);       // 4 MB
    float* x2 = (float*)(ws + (size_t)2 * NROWS * DK * 2);                     // 32 KB
    float* y2 = x2 + NROWS;                                                    // 32 KB

    prep_kernel<<<NROWS, 64, 0, stream>>>(x, y, xb, yb, x2, y2);

    gemm_ep_kernel<<<NROWS / BM * (NROWS / BN), 256, 0, stream>>>(xb, yb, x2, y2, out);
}

// Round 3
// 343.173 us; speedup vs baseline: 1.0700x; 1.0700x over previous
//
#include <hip/hip_runtime.h>
#include <hip/hip_bf16.h>
#include <cstdint>
#include <cstddef>

// K(x,y) = exp(-0.5*||x-y||^2) + 0.1*(x.y^T + 1)^3
// x,y: (8192, 256) fp32. out: (8192, 8192) fp32.
//
// R3: back to the R1 LDS structure (R2's no-LDS variant regressed: L2-latency
// bound). Change vs R1: T3-minimum 2-phase pipeline. BK=32, double-buffered
// LDS (2x8KB per operand = 32 KB total, same as R1), per K-iter:
//   issue STAGE(t+1) -> buf^1 ; ds_read+MFMA from buf ; one __syncthreads.
// The vmcnt(0) drain at the barrier lands AFTER compute, so the global->LDS
// latency is hidden under the MFMAs instead of exposed (R1 drained BEFORE
// compute every iteration). launch_bounds(256,4) caps VGPR at 128 -> 4
// blocks/CU. Epilogue stores are nontemporal so the 268 MB output stream
// doesn't evict the 3 MB/XCD input working set from L2.

#define NROWS 8192
#define DK    256
#define BM    128
#define BN    128
#define BK    32
#define NT    (DK / BK)   // 8 K-tiles

typedef __bf16 bf16_8 __attribute__((ext_vector_type(8)));
typedef float  f32x4  __attribute__((ext_vector_type(4)));

__device__ __forceinline__ unsigned short f2bf(float f) {
    unsigned int u = __builtin_bit_cast(unsigned int, f);
    u = (u + 0x7FFFu + ((u >> 16) & 1u)) >> 16;  // round-to-nearest-even
    return (unsigned short)u;
}

// ---------------------------------------------------------------------------
// Prep: fp32 -> bf16 conversion + row squared-norms (fp32, exact-ish).
// ---------------------------------------------------------------------------
__global__ __launch_bounds__(64) void prep_kernel(
    const float* __restrict__ x, const float* __restrict__ y,
    unsigned short* __restrict__ xb, unsigned short* __restrict__ yb,
    float* __restrict__ x2, float* __restrict__ y2)
{
    const int row  = blockIdx.x;
    const int lane = threadIdx.x;          // 0..63, 4 floats each = 256
    const size_t base = (size_t)row * DK + lane * 4;

    const float4 vx = *(const float4*)(x + base);
    const float4 vy = *(const float4*)(y + base);

    ushort4 hx = make_ushort4(f2bf(vx.x), f2bf(vx.y), f2bf(vx.z), f2bf(vx.w));
    ushort4 hy = make_ushort4(f2bf(vy.x), f2bf(vy.y), f2bf(vy.z), f2bf(vy.w));
    *(ushort4*)(xb + base) = hx;
    *(ushort4*)(yb + base) = hy;

    float sx = vx.x * vx.x + vx.y * vx.y + vx.z * vx.z + vx.w * vx.w;
    float sy = vy.x * vy.x + vy.y * vy.y + vy.z * vy.z + vy.w * vy.w;
    #pragma unroll
    for (int off = 32; off > 0; off >>= 1) {
        sx += __shfl_down(sx, off);
        sy += __shfl_down(sy, off);
    }
    if (lane == 0) {
        x2[row] = sx;
        y2[row] = sy;
    }
}

// ---------------------------------------------------------------------------
// GEMM + fused epilogue. C = x_bf @ y_bf^T with 16x16x32 bf16 MFMA.
// 4 waves in 2x2, each wave owns 64x64 (4x4 of 16x16 MFMA).
//
// LDS layout per buffer: [128 rows][4 slots of 16B], swizzled: LDS slot s of
// row r holds GLOBAL slot s ^ (r&3). Staging chunk = 16 rows = 1 KiB, linear
// LDS dest (global_load_lds requirement); lane l -> row l>>2, LDS slot l&3,
// so its pre-swizzled GLOBAL slot is (l&3) ^ ((l>>2)&3). Fragment read for
// global slot q (=quad) of row r reads LDS slot q ^ (r&3); bank histogram is
// uniform 8 accesses/bank -> conflict-free for wave64 ds_read_b128.
// ---------------------------------------------------------------------------
__global__ __launch_bounds__(256, 4) void gemm_ep_kernel(
    const unsigned short* __restrict__ xb, const unsigned short* __restrict__ yb,
    const float* __restrict__ x2, const float* __restrict__ y2,
    float* __restrict__ out)
{
    __shared__ __align__(16) unsigned short As[2 * BM * BK];  // 16 KB (2 bufs)
    __shared__ __align__(16) unsigned short Bs[2 * BN * BK];  // 16 KB

    const int tid  = threadIdx.x;
    const int wave = tid >> 6;
    const int lane = tid & 63;

    // XCD-chunked remap: xcd = id%8 (HW round-robin). Each XCD owns a
    // 32(bm) x 16(bn) rectangle -> per-XCD L2 working set 3 MB.
    const int id  = blockIdx.x;
    const int xcd = id & 7;
    const int idx = id >> 3;                   // 0..511
    const int bm  = (xcd & 1) * 32 + (idx & 31);
    const int bn  = (xcd >> 1) * 16 + (idx >> 5);

    const int wm = (wave & 1) * 64;   // wave's row offset in 128-tile
    const int wn = (wave >> 1) * 64;  // wave's col offset in 128-tile

    // --- staging: tile = 128 rows x 32 cols bf16 = 8 KB = 8 chunks of 1 KiB
    // (16 rows each). Wave w stages chunks 2w, 2w+1 of A and B (4 loads).
    const int srow  = lane >> 2;                 // 0..15 row within chunk
    const int gslot = (lane & 3) ^ (srow & 3);   // pre-swizzled global slot
    const size_t loff = (size_t)srow * DK + gslot * 8;

    const unsigned short* gA0 = xb + (size_t)(bm * BM + (wave * 2 + 0) * 16) * DK + loff;
    const unsigned short* gA1 = xb + (size_t)(bm * BM + (wave * 2 + 1) * 16) * DK + loff;
    const unsigned short* gB0 = yb + (size_t)(bn * BN + (wave * 2 + 0) * 16) * DK + loff;
    const unsigned short* gB1 = yb + (size_t)(bn * BN + (wave * 2 + 1) * 16) * DK + loff;
    unsigned short* lA0 = &As[(wave * 2 + 0) * 512];   // 512 ushort = 1 KiB
    unsigned short* lA1 = &As[(wave * 2 + 1) * 512];
    unsigned short* lB0 = &Bs[(wave * 2 + 0) * 512];
    unsigned short* lB1 = &Bs[(wave * 2 + 1) * 512];

    #define STAGE(t, buf) do {                                                  \
        __builtin_amdgcn_global_load_lds(                                       \
            (const __attribute__((address_space(1))) void*)(gA0 + (t) * BK),    \
            (__attribute__((address_space(3))) void*)(lA0 + (buf) * (BM * BK)), \
            16, 0, 0);                                                          \
        __builtin_amdgcn_global_load_lds(                                       \
            (const __attribute__((address_space(1))) void*)(gA1 + (t) * BK),    \
            (__attribute__((address_space(3))) void*)(lA1 + (buf) * (BM * BK)), \
            16, 0, 0);                                                          \
        __builtin_amdgcn_global_load_lds(                                       \
            (const __attribute__((address_space(1))) void*)(gB0 + (t) * BK),    \
            (__attribute__((address_space(3))) void*)(lB0 + (buf) * (BN * BK)), \
            16, 0, 0);                                                          \
        __builtin_amdgcn_global_load_lds(                                       \
            (const __attribute__((address_space(1))) void*)(gB1 + (t) * BK),    \
            (__attribute__((address_space(3))) void*)(lB1 + (buf) * (BN * BK)), \
            16, 0, 0);                                                          \
    } while (0)

    f32x4 acc[4][4];
    #pragma unroll
    for (int i = 0; i < 4; ++i)
        #pragma unroll
        for (int j = 0; j < 4; ++j)
            acc[i][j] = (f32x4){0.f, 0.f, 0.f, 0.f};

    const int quad = lane >> 4;   // 0..3 = global 16-B k-slot
    const int l15  = lane & 15;

    // Fragment read base (ushort index within a buffer); +i*16*BK per i-tile,
    // +buf*BM*BK per buffer (both compile-time under full unroll).
    const int aoff = (wm + l15) * BK + (quad ^ (l15 & 3)) * 8;
    const int boff = (wn + l15) * BK + (quad ^ (l15 & 3)) * 8;

    // --- 2-phase pipelined K-loop -----------------------------------------
    STAGE(0, 0);
    __syncthreads();                          // drain tile-0 staging

    #pragma unroll
    for (int t = 0; t < NT; ++t) {
        const int cur = t & 1;
        if (t + 1 < NT) STAGE(t + 1, cur ^ 1);   // prefetch overlaps compute

        bf16_8 afr[4], bfr[4];
        #pragma unroll
        for (int i = 0; i < 4; ++i)
            afr[i] = *(const bf16_8*)&As[cur * (BM * BK) + aoff + i * 16 * BK];
        #pragma unroll
        for (int j = 0; j < 4; ++j)
            bfr[j] = *(const bf16_8*)&Bs[cur * (BN * BK) + boff + j * 16 * BK];

        #pragma unroll
        for (int i = 0; i < 4; ++i)
            #pragma unroll
            for (int j = 0; j < 4; ++j)
                acc[i][j] = __builtin_amdgcn_mfma_f32_16x16x32_bf16(
                    afr[i], bfr[j], acc[i][j], 0, 0, 0);

        if (t + 1 < NT) __syncthreads();      // drains prefetch vmcnt AFTER compute
    }
    #undef STAGE

    // --- epilogue. C/D layout (verified m89/m91): col = lane&15, row = quad*4+reg
    const int mBase = bm * BM + wm + quad * 4;
    const int nBase = bn * BN + wn + l15;

    float y2v[4];
    #pragma unroll
    for (int j = 0; j < 4; ++j) y2v[j] = y2[nBase + j * 16];

    #pragma unroll
    for (int i = 0; i < 4; ++i) {
        #pragma unroll
        for (int r = 0; r < 4; ++r) {
            const int m = mBase + i * 16 + r;
            const float xv = x2[m];
            float* orow = out + (size_t)m * NROWS + nBase;
            #pragma unroll
            for (int j = 0; j < 4; ++j) {
                const float xy = acc[i][j][r];
                float s = xv + y2v[j] - 2.0f * xy;
                s = fmaxf(s, 0.0f);
                const float e = __expf(-0.5f * s);
                const float p = xy + 1.0f;
                __builtin_nontemporal_store(fmaf(0.1f, p * p * p, e), &orow[j * 16]);
            }
        }
    }
}

// ---------------------------------------------------------------------------
extern "C" void kernel_launch(void* const* d_in, const int* in_sizes, int n_in,
                              void* d_out, int out_size, void* d_ws, size_t ws_size,
                              hipStream_t stream) {
    const float* x = (const float*)d_in[0];
    const float* y = (const float*)d_in[1];
    float* out = (float*)d_out;

    char* ws = (char*)d_ws;
    unsigned short* xb = (unsigned short*)ws;                                  // 4 MB
    unsigned short* yb = (unsigned short*)(ws + (size_t)NROWS * DK * 2);       // 4 MB
    float* x2 = (float*)(ws + (size_t)2 * NROWS * DK * 2);                     // 32 KB
    float* y2 = x2 + NROWS;                                                    // 32 KB

    prep_kernel<<<NROWS, 64, 0, stream>>>(x, y, xb, yb, x2, y2);

    gemm_ep_kernel<<<(NROWS / BM) * (NROWS / BN), 256, 0, stream>>>(xb, yb, x2, y2, out);
}

// Round 4
// 339.773 us; speedup vs baseline: 1.0808x; 1.0100x over previous
//
#include <hip/hip_runtime.h>
#include <hip/hip_bf16.h>
#include <cstdint>
#include <cstddef>

// K(x,y) = exp(-0.5*||x-y||^2) + 0.1*(x.y^T + 1)^3
// x,y: (8192, 256) fp32. out: (8192, 8192) fp32.
//
// R4: A-persistent multi-tile blocks. 512 blocks (exactly 2/CU), each block
// fixes a 128-row A-panel, stages it ONCE full-K into LDS (64 KB), then walks
// 8 bn-tiles streaming only B (BK=32 chunks, 8 KB, double-buffered -> LDS
// total 80 KB = exactly 2 blocks/CU). Continuous K-chunk stream: 1 barrier
// per chunk, prefetch chunk c+1 during compute of c; at tile ends the next
// tile's B prefetch is hidden under the store/exp epilogue (epilogue touches
// no LDS). Swizzles (rule #21, both sides): A slot ^= row&7 (conflict-free),
// B slot ^= row&3 (2-way = free). Nontemporal stores protect L2 inputs.

#define NROWS 8192
#define DK    256
#define BM    128
#define BN    128
#define BK    32

typedef __bf16 bf16_8 __attribute__((ext_vector_type(8)));
typedef float  f32x4  __attribute__((ext_vector_type(4)));

__device__ __forceinline__ unsigned short f2bf(float f) {
    unsigned int u = __builtin_bit_cast(unsigned int, f);
    u = (u + 0x7FFFu + ((u >> 16) & 1u)) >> 16;  // round-to-nearest-even
    return (unsigned short)u;
}

// ---------------------------------------------------------------------------
// Prep: fp32 -> bf16 conversion + row squared-norms.
// ---------------------------------------------------------------------------
__global__ __launch_bounds__(64) void prep_kernel(
    const float* __restrict__ x, const float* __restrict__ y,
    unsigned short* __restrict__ xb, unsigned short* __restrict__ yb,
    float* __restrict__ x2, float* __restrict__ y2)
{
    const int row  = blockIdx.x;
    const int lane = threadIdx.x;          // 0..63, 4 floats each = 256
    const size_t base = (size_t)row * DK + lane * 4;

    const float4 vx = *(const float4*)(x + base);
    const float4 vy = *(const float4*)(y + base);

    ushort4 hx = make_ushort4(f2bf(vx.x), f2bf(vx.y), f2bf(vx.z), f2bf(vx.w));
    ushort4 hy = make_ushort4(f2bf(vy.x), f2bf(vy.y), f2bf(vy.z), f2bf(vy.w));
    *(ushort4*)(xb + base) = hx;
    *(ushort4*)(yb + base) = hy;

    float sx = vx.x * vx.x + vx.y * vx.y + vx.z * vx.z + vx.w * vx.w;
    float sy = vy.x * vy.x + vy.y * vy.y + vy.z * vy.z + vy.w * vy.w;
    #pragma unroll
    for (int off = 32; off > 0; off >>= 1) {
        sx += __shfl_down(sx, off);
        sy += __shfl_down(sy, off);
    }
    if (lane == 0) {
        x2[row] = sx;
        y2[row] = sy;
    }
}

// ---------------------------------------------------------------------------
// GEMM + fused epilogue, A-persistent.
//
// A LDS layout: [128 rows][32 slots of 16B], LDS[r][s] = Aglobal[r][s^(r&7)].
//   Stage: 64 chunks of 1 KiB (= 2 rows); lane l -> row 2c+(l>>5), LDS slot
//   l&31, so global slot (l&31)^(row&7). Read slot for global g: g^(r&7).
// B LDS layout (per 8 KB buffer): [128 rows][4 slots], LDS[r][s] =
//   Bglobal[r][s^(r&3)]. Stage: 8 sub-chunks of 1 KiB (= 16 rows); lane l ->
//   row 16*sc+(l>>2), slot l&3, global slot (l&3)^((l>>2)&3).
// ---------------------------------------------------------------------------
__global__ __launch_bounds__(256, 2) void gemm_ep_kernel(
    const unsigned short* __restrict__ xb, const unsigned short* __restrict__ yb,
    const float* __restrict__ x2, const float* __restrict__ y2,
    float* __restrict__ out)
{
    __shared__ __align__(16) unsigned short As[BM * DK];       // 64 KB
    __shared__ __align__(16) unsigned short Bs[2 * BN * BK];   // 16 KB

    const int tid  = threadIdx.x;
    const int wave = tid >> 6;
    const int lane = tid & 63;

    // XCD map: xcd = id&7 (HW round-robin). Each XCD: 16 bm x 4 grp ->
    // working set 1 MB (A) + 2 MB (B) < 4 MB L2. Bijective (512 blocks).
    const int id  = blockIdx.x;
    const int xcd = id & 7;
    const int i2  = id >> 3;                    // 0..63
    const int bm  = (xcd >> 1) * 16 + (i2 & 15);   // 0..63
    const int grp = (xcd & 1) * 4 + (i2 >> 4);     // 0..7

    const int wm   = (wave & 1) * 64;
    const int wn   = (wave >> 1) * 64;
    const int quad = lane >> 4;     // 0..3
    const int l15  = lane & 15;
    const int l7   = l15 & 7;
    const int l3   = l15 & 3;

    // ---- A stage: 16 chunks per wave, chunk = 2 rows = 1 KiB ----
    #pragma unroll
    for (int u = 0; u < 16; ++u) {
        const int c   = wave * 16 + u;
        const int row = 2 * c + (lane >> 5);                 // tile row 0..127
        const int g   = (lane & 31) ^ (row & 7);             // global 16B slot
        const unsigned short* src = xb + (size_t)(bm * BM + row) * DK + g * 8;
        __builtin_amdgcn_global_load_lds(
            (const __attribute__((address_space(1))) void*)src,
            (__attribute__((address_space(3))) void*)(As + c * 512),
            16, 0, 0);
    }

    // ---- B staging setup: per wave 2 sub-chunks (16 rows each) ----
    const int brow0 = (wave * 2) * 16 + (lane >> 2);         // row of sub-chunk 0
    const int bg    = (lane & 3) ^ ((lane >> 2) & 3);        // pre-swz global slot
    const size_t bsrc0 = (size_t)brow0 * DK + bg * 8;        // sub1 = +4096
    unsigned short* bdst0 = Bs + (wave * 2) * 512;           // sub1 = +512

    #define STAGE_B(PTR, PD) do {                                               \
        __builtin_amdgcn_global_load_lds(                                       \
            (const __attribute__((address_space(1))) void*)(PTR),               \
            (__attribute__((address_space(3))) void*)(PD), 16, 0, 0);           \
        __builtin_amdgcn_global_load_lds(                                       \
            (const __attribute__((address_space(1))) void*)((PTR) + 4096),      \
            (__attribute__((address_space(3))) void*)((PD) + 512), 16, 0, 0);   \
    } while (0)

    // gBstage walks the 64 B-chunks (8 tiles x 8 k-chunks) for this block.
    const unsigned short* gBstage =
        yb + (size_t)(grp * 8) * (BN * DK) + bsrc0;

    STAGE_B(gBstage, bdst0);          // chunk 0 -> buf 0
    gBstage += 32;                    // -> chunk 1
    __syncthreads();                  // A + B chunk 0 resident

    // ---- accumulators + hoisted x2 ----
    f32x4 acc[4][4];
    #pragma unroll
    for (int i = 0; i < 4; ++i)
        #pragma unroll
        for (int j = 0; j < 4; ++j)
            acc[i][j] = (f32x4){0.f, 0.f, 0.f, 0.f};

    const int mBase = bm * BM + wm + quad * 4;
    float xv[4][4];
    #pragma unroll
    for (int i = 0; i < 4; ++i)
        #pragma unroll
        for (int r = 0; r < 4; ++r)
            xv[i][r] = x2[mBase + i * 16 + r];

    const int arow  = (wm + l15) * DK;                 // A row base (ushorts)
    const int bbase = (wn + l15) * BK + (quad ^ l3) * 8;

    int p  = 0;
    int bn = grp * 8;

    for (int tile = 0; tile < 8; ++tile) {
        #pragma unroll
        for (int tk = 0; tk < 8; ++tk) {
            // prefetch next chunk (skip only at the very last chunk)
            if (tk < 7 || tile < 7)
                STAGE_B(gBstage, bdst0 + (p ^ 1) * 4096);
            gBstage += (tk == 6) ? (BN * DK - 7 * 32) : 32;

            // fragments from LDS
            bf16_8 afr[4], bfr[4];
            const int sA = ((tk << 2) | quad) ^ l7;    // A swizzled slot
            #pragma unroll
            for (int i = 0; i < 4; ++i)
                afr[i] = *(const bf16_8*)&As[arow + i * 16 * DK + sA * 8];
            #pragma unroll
            for (int j = 0; j < 4; ++j)
                bfr[j] = *(const bf16_8*)&Bs[p * 4096 + bbase + j * 16 * BK];

            #pragma unroll
            for (int i = 0; i < 4; ++i)
                #pragma unroll
                for (int j = 0; j < 4; ++j)
                    acc[i][j] = __builtin_amdgcn_mfma_f32_16x16x32_bf16(
                        afr[i], bfr[j], acc[i][j], 0, 0, 0);

            if (tk == 7) {
                // ---- epilogue for this tile (no LDS: overlaps B prefetch) --
                const int nBase = bn * BN + wn + l15;
                float y2v[4];
                #pragma unroll
                for (int j = 0; j < 4; ++j) y2v[j] = y2[nBase + j * 16];

                #pragma unroll
                for (int i = 0; i < 4; ++i) {
                    #pragma unroll
                    for (int r = 0; r < 4; ++r) {
                        const int m = mBase + i * 16 + r;
                        float* orow = out + (size_t)m * NROWS + nBase;
                        const float xvv = xv[i][r];
                        #pragma unroll
                        for (int j = 0; j < 4; ++j) {
                            const float xy = acc[i][j][r];
                            float s = xvv + y2v[j] - 2.0f * xy;
                            s = fmaxf(s, 0.0f);
                            const float e = __expf(-0.5f * s);
                            const float pq = xy + 1.0f;
                            __builtin_nontemporal_store(
                                fmaf(0.1f, pq * pq * pq, e), &orow[j * 16]);
                        }
                    }
                }
                // reset accumulators for next tile
                #pragma unroll
                for (int i = 0; i < 4; ++i)
                    #pragma unroll
                    for (int j = 0; j < 4; ++j)
                        acc[i][j] = (f32x4){0.f, 0.f, 0.f, 0.f};
                bn += 1;
            }
            __syncthreads();
            p ^= 1;
        }
    }
    #undef STAGE_B
}

// ---------------------------------------------------------------------------
extern "C" void kernel_launch(void* const* d_in, const int* in_sizes, int n_in,
                              void* d_out, int out_size, void* d_ws, size_t ws_size,
                              hipStream_t stream) {
    const float* x = (const float*)d_in[0];
    const float* y = (const float*)d_in[1];
    float* out = (float*)d_out;

    char* ws = (char*)d_ws;
    unsigned short* xb = (unsigned short*)ws;                                  // 4 MB
    unsigned short* yb = (unsigned short*)(ws + (size_t)NROWS * DK * 2);       // 4 MB
    float* x2 = (float*)(ws + (size_t)2 * NROWS * DK * 2);                     // 32 KB
    float* y2 = x2 + NROWS;                                                    // 32 KB

    prep_kernel<<<NROWS, 64, 0, stream>>>(x, y, xb, yb, x2, y2);

    gemm_ep_kernel<<<512, 256, 0, stream>>>(xb, yb, x2, y2, out);
}

// Round 5
// 311.303 us; speedup vs baseline: 1.1796x; 1.0915x over previous
//
#include <hip/hip_runtime.h>
#include <hip/hip_bf16.h>
#include <cstdint>
#include <cstddef>

// K(x,y) = exp(-0.5*||x-y||^2) + 0.1*(x.y^T + 1)^3
// x,y: (8192, 256) fp32. out: (8192, 8192) fp32.
//
// R5 == R4 with ONE change: plain stores instead of nontemporal.
// Theory: R3 and R4 both regressed ~+50us vs R1 with disjoint structures but
// shared __builtin_nontemporal_store; NT bypasses L2 write-combining ->
// 64-B HBM granules -> ~2x write amplification on the 268 MB output
// (43us -> ~90us). Normal stores let L2 coalesce the 64-B wave segments
// into full HBM bursts.
//
// Structure (from R4): A-persistent multi-tile blocks. 512 blocks (2/CU),
// each fixes a 128-row A-panel, stages it once full-K into LDS (64 KB), then
// walks 8 bn-tiles streaming only B (BK=32 chunks, 8 KB double-buffered ->
// LDS 80 KB). One barrier per chunk; B prefetch of chunk c+1 in flight during
// compute of c; at tile ends the prefetch lands under the LDS-free epilogue.
// Swizzles (rule #21, both sides): A slot ^= row&7, B slot ^= row&3.

#define NROWS 8192
#define DK    256
#define BM    128
#define BN    128
#define BK    32

typedef __bf16 bf16_8 __attribute__((ext_vector_type(8)));
typedef float  f32x4  __attribute__((ext_vector_type(4)));

__device__ __forceinline__ unsigned short f2bf(float f) {
    unsigned int u = __builtin_bit_cast(unsigned int, f);
    u = (u + 0x7FFFu + ((u >> 16) & 1u)) >> 16;  // round-to-nearest-even
    return (unsigned short)u;
}

// ---------------------------------------------------------------------------
// Prep: fp32 -> bf16 conversion + row squared-norms.
// ---------------------------------------------------------------------------
__global__ __launch_bounds__(64) void prep_kernel(
    const float* __restrict__ x, const float* __restrict__ y,
    unsigned short* __restrict__ xb, unsigned short* __restrict__ yb,
    float* __restrict__ x2, float* __restrict__ y2)
{
    const int row  = blockIdx.x;
    const int lane = threadIdx.x;          // 0..63, 4 floats each = 256
    const size_t base = (size_t)row * DK + lane * 4;

    const float4 vx = *(const float4*)(x + base);
    const float4 vy = *(const float4*)(y + base);

    ushort4 hx = make_ushort4(f2bf(vx.x), f2bf(vx.y), f2bf(vx.z), f2bf(vx.w));
    ushort4 hy = make_ushort4(f2bf(vy.x), f2bf(vy.y), f2bf(vy.z), f2bf(vy.w));
    *(ushort4*)(xb + base) = hx;
    *(ushort4*)(yb + base) = hy;

    float sx = vx.x * vx.x + vx.y * vx.y + vx.z * vx.z + vx.w * vx.w;
    float sy = vy.x * vy.x + vy.y * vy.y + vy.z * vy.z + vy.w * vy.w;
    #pragma unroll
    for (int off = 32; off > 0; off >>= 1) {
        sx += __shfl_down(sx, off);
        sy += __shfl_down(sy, off);
    }
    if (lane == 0) {
        x2[row] = sx;
        y2[row] = sy;
    }
}

// ---------------------------------------------------------------------------
// GEMM + fused epilogue, A-persistent.
//
// A LDS layout: [128 rows][32 slots of 16B], LDS[r][s] = Aglobal[r][s^(r&7)].
// B LDS layout (per 8 KB buffer): [128 rows][4 slots], LDS[r][s] =
//   Bglobal[r][s^(r&3)].
// ---------------------------------------------------------------------------
__global__ __launch_bounds__(256, 2) void gemm_ep_kernel(
    const unsigned short* __restrict__ xb, const unsigned short* __restrict__ yb,
    const float* __restrict__ x2, const float* __restrict__ y2,
    float* __restrict__ out)
{
    __shared__ __align__(16) unsigned short As[BM * DK];       // 64 KB
    __shared__ __align__(16) unsigned short Bs[2 * BN * BK];   // 16 KB

    const int tid  = threadIdx.x;
    const int wave = tid >> 6;
    const int lane = tid & 63;

    // XCD map: xcd = id&7 (HW round-robin). Each XCD: 16 bm x 4 grp ->
    // working set 1 MB (A) + 2 MB (B) < 4 MB L2. Bijective (512 blocks).
    const int id  = blockIdx.x;
    const int xcd = id & 7;
    const int i2  = id >> 3;                    // 0..63
    const int bm  = (xcd >> 1) * 16 + (i2 & 15);   // 0..63
    const int grp = (xcd & 1) * 4 + (i2 >> 4);     // 0..7

    const int wm   = (wave & 1) * 64;
    const int wn   = (wave >> 1) * 64;
    const int quad = lane >> 4;     // 0..3
    const int l15  = lane & 15;
    const int l7   = l15 & 7;
    const int l3   = l15 & 3;

    // ---- A stage: 16 chunks per wave, chunk = 2 rows = 1 KiB ----
    #pragma unroll
    for (int u = 0; u < 16; ++u) {
        const int c   = wave * 16 + u;
        const int row = 2 * c + (lane >> 5);                 // tile row 0..127
        const int g   = (lane & 31) ^ (row & 7);             // global 16B slot
        const unsigned short* src = xb + (size_t)(bm * BM + row) * DK + g * 8;
        __builtin_amdgcn_global_load_lds(
            (const __attribute__((address_space(1))) void*)src,
            (__attribute__((address_space(3))) void*)(As + c * 512),
            16, 0, 0);
    }

    // ---- B staging setup: per wave 2 sub-chunks (16 rows each) ----
    const int brow0 = (wave * 2) * 16 + (lane >> 2);         // row of sub-chunk 0
    const int bg    = (lane & 3) ^ ((lane >> 2) & 3);        // pre-swz global slot
    const size_t bsrc0 = (size_t)brow0 * DK + bg * 8;        // sub1 = +4096
    unsigned short* bdst0 = Bs + (wave * 2) * 512;           // sub1 = +512

    #define STAGE_B(PTR, PD) do {                                               \
        __builtin_amdgcn_global_load_lds(                                       \
            (const __attribute__((address_space(1))) void*)(PTR),               \
            (__attribute__((address_space(3))) void*)(PD), 16, 0, 0);           \
        __builtin_amdgcn_global_load_lds(                                       \
            (const __attribute__((address_space(1))) void*)((PTR) + 4096),      \
            (__attribute__((address_space(3))) void*)((PD) + 512), 16, 0, 0);   \
    } while (0)

    // gBstage walks the 64 B-chunks (8 tiles x 8 k-chunks) for this block.
    const unsigned short* gBstage =
        yb + (size_t)(grp * 8) * (BN * DK) + bsrc0;

    STAGE_B(gBstage, bdst0);          // chunk 0 -> buf 0
    gBstage += 32;                    // -> chunk 1
    __syncthreads();                  // A + B chunk 0 resident

    // ---- accumulators + hoisted x2 ----
    f32x4 acc[4][4];
    #pragma unroll
    for (int i = 0; i < 4; ++i)
        #pragma unroll
        for (int j = 0; j < 4; ++j)
            acc[i][j] = (f32x4){0.f, 0.f, 0.f, 0.f};

    const int mBase = bm * BM + wm + quad * 4;
    float xv[4][4];
    #pragma unroll
    for (int i = 0; i < 4; ++i)
        #pragma unroll
        for (int r = 0; r < 4; ++r)
            xv[i][r] = x2[mBase + i * 16 + r];

    const int arow  = (wm + l15) * DK;                 // A row base (ushorts)
    const int bbase = (wn + l15) * BK + (quad ^ l3) * 8;

    int p  = 0;
    int bn = grp * 8;

    for (int tile = 0; tile < 8; ++tile) {
        #pragma unroll
        for (int tk = 0; tk < 8; ++tk) {
            // prefetch next chunk (skip only at the very last chunk)
            if (tk < 7 || tile < 7)
                STAGE_B(gBstage, bdst0 + (p ^ 1) * 4096);
            gBstage += (tk == 6) ? (BN * DK - 7 * 32) : 32;

            // fragments from LDS
            bf16_8 afr[4], bfr[4];
            const int sA = ((tk << 2) | quad) ^ l7;    // A swizzled slot
            #pragma unroll
            for (int i = 0; i < 4; ++i)
                afr[i] = *(const bf16_8*)&As[arow + i * 16 * DK + sA * 8];
            #pragma unroll
            for (int j = 0; j < 4; ++j)
                bfr[j] = *(const bf16_8*)&Bs[p * 4096 + bbase + j * 16 * BK];

            #pragma unroll
            for (int i = 0; i < 4; ++i)
                #pragma unroll
                for (int j = 0; j < 4; ++j)
                    acc[i][j] = __builtin_amdgcn_mfma_f32_16x16x32_bf16(
                        afr[i], bfr[j], acc[i][j], 0, 0, 0);

            if (tk == 7) {
                // ---- epilogue for this tile (no LDS: overlaps B prefetch) --
                const int nBase = bn * BN + wn + l15;
                float y2v[4];
                #pragma unroll
                for (int j = 0; j < 4; ++j) y2v[j] = y2[nBase + j * 16];

                #pragma unroll
                for (int i = 0; i < 4; ++i) {
                    #pragma unroll
                    for (int r = 0; r < 4; ++r) {
                        const int m = mBase + i * 16 + r;
                        float* orow = out + (size_t)m * NROWS + nBase;
                        const float xvv = xv[i][r];
                        #pragma unroll
                        for (int j = 0; j < 4; ++j) {
                            const float xy = acc[i][j][r];
                            float s = xvv + y2v[j] - 2.0f * xy;
                            s = fmaxf(s, 0.0f);
                            const float e = __expf(-0.5f * s);
                            const float pq = xy + 1.0f;
                            orow[j * 16] = fmaf(0.1f, pq * pq * pq, e);
                        }
                    }
                }
                // reset accumulators for next tile
                #pragma unroll
                for (int i = 0; i < 4; ++i)
                    #pragma unroll
                    for (int j = 0; j < 4; ++j)
                        acc[i][j] = (f32x4){0.f, 0.f, 0.f, 0.f};
                bn += 1;
            }
            __syncthreads();
            p ^= 1;
        }
    }
    #undef STAGE_B
}

// ---------------------------------------------------------------------------
extern "C" void kernel_launch(void* const* d_in, const int* in_sizes, int n_in,
                              void* d_out, int out_size, void* d_ws, size_t ws_size,
                              hipStream_t stream) {
    const float* x = (const float*)d_in[0];
    const float* y = (const float*)d_in[1];
    float* out = (float*)d_out;

    char* ws = (char*)d_ws;
    unsigned short* xb = (unsigned short*)ws;                                  // 4 MB
    unsigned short* yb = (unsigned short*)(ws + (size_t)NROWS * DK * 2);       // 4 MB
    float* x2 = (float*)(ws + (size_t)2 * NROWS * DK * 2);                     // 32 KB
    float* y2 = x2 + NROWS;                                                    // 32 KB

    prep_kernel<<<NROWS, 64, 0, stream>>>(x, y, xb, yb, x2, y2);

    gemm_ep_kernel<<<512, 256, 0, stream>>>(xb, yb, x2, y2, out);
}

// Round 6
// 307.022 us; speedup vs baseline: 1.1960x; 1.0139x over previous
//
#include <hip/hip_runtime.h>
#include <hip/hip_bf16.h>
#include <cstdint>
#include <cstddef>

// K(x,y) = exp(-0.5*||x-y||^2) + 0.1*(x.y^T + 1)^3
// x,y: (8192, 256) fp32. out: (8192, 8192) fp32.
//
// R6 = R3's 2-phase double-buffered pipeline with BOTH confounders removed:
//   - plain stores (R5 proved nontemporal costs ~+29us: NT bypasses L2
//     write-combining -> 64-B HBM granules -> write amplification)
//   - no forced min-waves (R3's __launch_bounds__(256,4) capped VGPR at 128
//     -> spill pressure). Natural VGPR ~120 -> ~4 blocks/CU.
// Structure: BK=32, double-buffered LDS (2x8KB/operand = 32 KB), per K-iter:
//   issue STAGE(t+1) -> buf^1 ; ds_read+MFMA from buf ; one __syncthreads.
// The vmcnt drain lands AFTER 32 MFMAs instead of before them (R1 exposes
// the full global->LDS latency before compute at every iteration).
// Swizzles (rule #21, both sides; correctness-verified by R3's pass):
// LDS slot s of row r holds GLOBAL slot s^(r&3).

#define NROWS 8192
#define DK    256
#define BM    128
#define BN    128
#define BK    32
#define NT    (DK / BK)   // 8 K-tiles

typedef __bf16 bf16_8 __attribute__((ext_vector_type(8)));
typedef float  f32x4  __attribute__((ext_vector_type(4)));

__device__ __forceinline__ unsigned short f2bf(float f) {
    unsigned int u = __builtin_bit_cast(unsigned int, f);
    u = (u + 0x7FFFu + ((u >> 16) & 1u)) >> 16;  // round-to-nearest-even
    return (unsigned short)u;
}

// ---------------------------------------------------------------------------
// Prep: fp32 -> bf16 conversion + row squared-norms.
// ---------------------------------------------------------------------------
__global__ __launch_bounds__(64) void prep_kernel(
    const float* __restrict__ x, const float* __restrict__ y,
    unsigned short* __restrict__ xb, unsigned short* __restrict__ yb,
    float* __restrict__ x2, float* __restrict__ y2)
{
    const int row  = blockIdx.x;
    const int lane = threadIdx.x;          // 0..63, 4 floats each = 256
    const size_t base = (size_t)row * DK + lane * 4;

    const float4 vx = *(const float4*)(x + base);
    const float4 vy = *(const float4*)(y + base);

    ushort4 hx = make_ushort4(f2bf(vx.x), f2bf(vx.y), f2bf(vx.z), f2bf(vx.w));
    ushort4 hy = make_ushort4(f2bf(vy.x), f2bf(vy.y), f2bf(vy.z), f2bf(vy.w));
    *(ushort4*)(xb + base) = hx;
    *(ushort4*)(yb + base) = hy;

    float sx = vx.x * vx.x + vx.y * vx.y + vx.z * vx.z + vx.w * vx.w;
    float sy = vy.x * vy.x + vy.y * vy.y + vy.z * vy.z + vy.w * vy.w;
    #pragma unroll
    for (int off = 32; off > 0; off >>= 1) {
        sx += __shfl_down(sx, off);
        sy += __shfl_down(sy, off);
    }
    if (lane == 0) {
        x2[row] = sx;
        y2[row] = sy;
    }
}

// ---------------------------------------------------------------------------
// GEMM + fused epilogue. C = x_bf @ y_bf^T with 16x16x32 bf16 MFMA.
// 4 waves in 2x2, each wave owns 64x64 (4x4 of 16x16 MFMA).
//
// LDS layout per buffer: [128 rows][4 slots of 16B], LDS[r][s] =
// global[r][s^(r&3)]. Staging chunk = 16 rows = 1 KiB, linear LDS dest;
// lane l -> row l>>2, LDS slot l&3, pre-swizzled GLOBAL slot (l&3)^((l>>2)&3).
// Fragment read for global slot q of row r reads LDS slot q^(r&3); bank
// histogram uniform -> conflict-free wave64 ds_read_b128.
// ---------------------------------------------------------------------------
__global__ __launch_bounds__(256) void gemm_ep_kernel(
    const unsigned short* __restrict__ xb, const unsigned short* __restrict__ yb,
    const float* __restrict__ x2, const float* __restrict__ y2,
    float* __restrict__ out)
{
    __shared__ __align__(16) unsigned short As[2 * BM * BK];  // 16 KB (2 bufs)
    __shared__ __align__(16) unsigned short Bs[2 * BN * BK];  // 16 KB

    const int tid  = threadIdx.x;
    const int wave = tid >> 6;
    const int lane = tid & 63;

    // XCD-chunked remap: xcd = id%8 (HW round-robin). Each XCD owns a
    // 32(bm) x 16(bn) rectangle -> per-XCD L2 working set 3 MB.
    const int id  = blockIdx.x;
    const int xcd = id & 7;
    const int idx = id >> 3;                   // 0..511
    const int bm  = (xcd & 1) * 32 + (idx & 31);
    const int bn  = (xcd >> 1) * 16 + (idx >> 5);

    const int wm = (wave & 1) * 64;   // wave's row offset in 128-tile
    const int wn = (wave >> 1) * 64;  // wave's col offset in 128-tile

    // --- staging: tile = 128 rows x 32 cols bf16 = 8 KB = 8 chunks of 1 KiB
    // (16 rows each). Wave w stages chunks 2w, 2w+1 of A and B (4 loads).
    const int srow  = lane >> 2;                 // 0..15 row within chunk
    const int gslot = (lane & 3) ^ (srow & 3);   // pre-swizzled global slot
    const size_t loff = (size_t)srow * DK + gslot * 8;

    const unsigned short* gA0 = xb + (size_t)(bm * BM + (wave * 2 + 0) * 16) * DK + loff;
    const unsigned short* gA1 = xb + (size_t)(bm * BM + (wave * 2 + 1) * 16) * DK + loff;
    const unsigned short* gB0 = yb + (size_t)(bn * BN + (wave * 2 + 0) * 16) * DK + loff;
    const unsigned short* gB1 = yb + (size_t)(bn * BN + (wave * 2 + 1) * 16) * DK + loff;
    unsigned short* lA0 = &As[(wave * 2 + 0) * 512];   // 512 ushort = 1 KiB
    unsigned short* lA1 = &As[(wave * 2 + 1) * 512];
    unsigned short* lB0 = &Bs[(wave * 2 + 0) * 512];
    unsigned short* lB1 = &Bs[(wave * 2 + 1) * 512];

    #define STAGE(t, buf) do {                                                  \
        __builtin_amdgcn_global_load_lds(                                       \
            (const __attribute__((address_space(1))) void*)(gA0 + (t) * BK),    \
            (__attribute__((address_space(3))) void*)(lA0 + (buf) * (BM * BK)), \
            16, 0, 0);                                                          \
        __builtin_amdgcn_global_load_lds(                                       \
            (const __attribute__((address_space(1))) void*)(gA1 + (t) * BK),    \
            (__attribute__((address_space(3))) void*)(lA1 + (buf) * (BM * BK)), \
            16, 0, 0);                                                          \
        __builtin_amdgcn_global_load_lds(                                       \
            (const __attribute__((address_space(1))) void*)(gB0 + (t) * BK),    \
            (__attribute__((address_space(3))) void*)(lB0 + (buf) * (BN * BK)), \
            16, 0, 0);                                                          \
        __builtin_amdgcn_global_load_lds(                                       \
            (const __attribute__((address_space(1))) void*)(gB1 + (t) * BK),    \
            (__attribute__((address_space(3))) void*)(lB1 + (buf) * (BN * BK)), \
            16, 0, 0);                                                          \
    } while (0)

    f32x4 acc[4][4];
    #pragma unroll
    for (int i = 0; i < 4; ++i)
        #pragma unroll
        for (int j = 0; j < 4; ++j)
            acc[i][j] = (f32x4){0.f, 0.f, 0.f, 0.f};

    const int quad = lane >> 4;   // 0..3 = global 16-B k-slot
    const int l15  = lane & 15;

    // Fragment read base (ushort index within a buffer); +i*16*BK per i-tile,
    // +buf*BM*BK per buffer (both compile-time under full unroll).
    const int aoff = (wm + l15) * BK + (quad ^ (l15 & 3)) * 8;
    const int boff = (wn + l15) * BK + (quad ^ (l15 & 3)) * 8;

    // --- 2-phase pipelined K-loop -----------------------------------------
    STAGE(0, 0);
    __syncthreads();                          // drain tile-0 staging

    #pragma unroll
    for (int t = 0; t < NT; ++t) {
        const int cur = t & 1;
        if (t + 1 < NT) STAGE(t + 1, cur ^ 1);   // prefetch overlaps compute

        bf16_8 afr[4], bfr[4];
        #pragma unroll
        for (int i = 0; i < 4; ++i)
            afr[i] = *(const bf16_8*)&As[cur * (BM * BK) + aoff + i * 16 * BK];
        #pragma unroll
        for (int j = 0; j < 4; ++j)
            bfr[j] = *(const bf16_8*)&Bs[cur * (BN * BK) + boff + j * 16 * BK];

        #pragma unroll
        for (int i = 0; i < 4; ++i)
            #pragma unroll
            for (int j = 0; j < 4; ++j)
                acc[i][j] = __builtin_amdgcn_mfma_f32_16x16x32_bf16(
                    afr[i], bfr[j], acc[i][j], 0, 0, 0);

        if (t + 1 < NT) __syncthreads();      // drains prefetch vmcnt AFTER compute
    }
    #undef STAGE

    // --- epilogue. C/D layout (verified m89/m91): col = lane&15, row = quad*4+reg
    const int mBase = bm * BM + wm + quad * 4;
    const int nBase = bn * BN + wn + l15;

    float y2v[4];
    #pragma unroll
    for (int j = 0; j < 4; ++j) y2v[j] = y2[nBase + j * 16];

    #pragma unroll
    for (int i = 0; i < 4; ++i) {
        #pragma unroll
        for (int r = 0; r < 4; ++r) {
            const int m = mBase + i * 16 + r;
            const float xv = x2[m];
            float* orow = out + (size_t)m * NROWS + nBase;
            #pragma unroll
            for (int j = 0; j < 4; ++j) {
                const float xy = acc[i][j][r];
                float s = xv + y2v[j] - 2.0f * xy;
                s = fmaxf(s, 0.0f);
                const float e = __expf(-0.5f * s);
                const float p = xy + 1.0f;
                orow[j * 16] = fmaf(0.1f, p * p * p, e);
            }
        }
    }
}

// ---------------------------------------------------------------------------
extern "C" void kernel_launch(void* const* d_in, const int* in_sizes, int n_in,
                              void* d_out, int out_size, void* d_ws, size_t ws_size,
                              hipStream_t stream) {
    const float* x = (const float*)d_in[0];
    const float* y = (const float*)d_in[1];
    float* out = (float*)d_out;

    char* ws = (char*)d_ws;
    unsigned short* xb = (unsigned short*)ws;                                  // 4 MB
    unsigned short* yb = (unsigned short*)(ws + (size_t)NROWS * DK * 2);       // 4 MB
    float* x2 = (float*)(ws + (size_t)2 * NROWS * DK * 2);                     // 32 KB
    float* y2 = x2 + NROWS;                                                    // 32 KB

    prep_kernel<<<NROWS, 64, 0, stream>>>(x, y, xb, yb, x2, y2);

    gemm_ep_kernel<<<(NROWS / BM) * (NROWS / BN), 256, 0, stream>>>(xb, yb, x2, y2, out);
}

// Round 7
// 294.032 us; speedup vs baseline: 1.2489x; 1.0442x over previous
//
#include <hip/hip_runtime.h>
#include <hip/hip_bf16.h>
#include <cstdint>
#include <cstddef>

// K(x,y) = exp(-0.5*||x-y||^2) + 0.1*(x.y^T + 1)^3
// x,y: (8192, 256) fp32. out: (8192, 8192) fp32.
//
// R7 = R1's frame (best: 290us; BK=64 single-buffered lockstep, both-sides
// row&7 XOR swizzle, plain stores, 2D grid) with ONE change: 32x32x16 MFMA
// instead of 16x16x32.
//   - matrix pipe: 16 MFMA x 8.07cyc vs 32 x 4.85cyc per K-tile/wave (-17%
//     pipe cycles, -50% MFMA instruction count -> issue headroom for ds_read)
//   - stores: C/D layout col=lane&31 -> each store instr writes 2 x 128-B
//     segments (vs 4 x 64-B), and the epilogue emits both 128-B halves of a
//     row back-to-back (256 B contiguous per row per wave).
// Everything else byte-equivalent to R1: staging chunks, swizzle, barriers.

#define NROWS 8192
#define DK    256
#define BM    128
#define BN    128
#define BK    64

typedef __bf16 bf16_8 __attribute__((ext_vector_type(8)));
typedef float  f32x16 __attribute__((ext_vector_type(16)));

__device__ __forceinline__ unsigned short f2bf(float f) {
    unsigned int u = __builtin_bit_cast(unsigned int, f);
    u = (u + 0x7FFFu + ((u >> 16) & 1u)) >> 16;  // round-to-nearest-even
    return (unsigned short)u;
}

// ---------------------------------------------------------------------------
// Prep: fp32 -> bf16 conversion + row squared-norms (fp32, exact-ish).
// One wave per row pair (x row b, y row b). 8192 blocks x 64 threads.
// ---------------------------------------------------------------------------
__global__ __launch_bounds__(64) void prep_kernel(
    const float* __restrict__ x, const float* __restrict__ y,
    unsigned short* __restrict__ xb, unsigned short* __restrict__ yb,
    float* __restrict__ x2, float* __restrict__ y2)
{
    const int row  = blockIdx.x;
    const int lane = threadIdx.x;          // 0..63, 4 floats each = 256
    const size_t base = (size_t)row * DK + lane * 4;

    const float4 vx = *(const float4*)(x + base);
    const float4 vy = *(const float4*)(y + base);

    ushort4 hx = make_ushort4(f2bf(vx.x), f2bf(vx.y), f2bf(vx.z), f2bf(vx.w));
    ushort4 hy = make_ushort4(f2bf(vy.x), f2bf(vy.y), f2bf(vy.z), f2bf(vy.w));
    *(ushort4*)(xb + base) = hx;
    *(ushort4*)(yb + base) = hy;

    float sx = vx.x * vx.x + vx.y * vx.y + vx.z * vx.z + vx.w * vx.w;
    float sy = vy.x * vy.x + vy.y * vy.y + vy.z * vy.z + vy.w * vy.w;
    #pragma unroll
    for (int off = 32; off > 0; off >>= 1) {
        sx += __shfl_down(sx, off);
        sy += __shfl_down(sy, off);
    }
    if (lane == 0) {
        x2[row] = sx;
        y2[row] = sy;
    }
}

// ---------------------------------------------------------------------------
// GEMM + fused epilogue. C = x_bf @ y_bf^T with 32x32x16 bf16 MFMA.
// Block = 256 threads = 4 waves in 2x2; each wave owns 64x64 = 2x2 grid of
// 32x32 MFMA tiles. Single-buffered LDS, 2-barrier K-loop, BK=64.
//
// LDS layout per operand: [128 rows][8 slots of 16B], LDS[r][s] =
// Gglobal[r][s^(r&7)]. Staging (linear dest, rule #21): chunk = 8 rows =
// 1 KiB; lane l -> row l>>3, LDS slot l&7, pre-swizzled GLOBAL slot
// (l&7)^(l>>3). Fragment read for global slot g of row r: LDS slot g^(r&7).
//
// 32x32x16 operand layout: A/B lane mapping row=lane&31, k=(lane>>5)*8+e
// -> per k-step ks (K=16): global slot g = 2*ks + (lane>>5), one b128 read.
// Bank histogram: 8 lanes per slot value, uniform -> conflict-free.
// ---------------------------------------------------------------------------
__global__ __launch_bounds__(256) void gemm_ep_kernel(
    const unsigned short* __restrict__ xb, const unsigned short* __restrict__ yb,
    const float* __restrict__ x2, const float* __restrict__ y2,
    float* __restrict__ out)
{
    __shared__ __align__(16) unsigned short As[BM * BK];  // 16 KB
    __shared__ __align__(16) unsigned short Bs[BN * BK];  // 16 KB

    const int tid  = threadIdx.x;
    const int wave = tid >> 6;
    const int lane = tid & 63;
    const int bm   = blockIdx.x;
    const int bn   = blockIdx.y;

    const int wm = (wave & 1) * 64;   // wave's row offset in 128-tile
    const int wn = (wave >> 1) * 64;  // wave's col offset in 128-tile

    // --- staging: tile is 128 rows x 64 cols bf16 = 16 KB = 16 chunks of
    // 1 KiB. Wave w stages chunks 4w..4w+3 of A and B (8 global_load_lds).
    const int subrow = lane >> 3;                 // 0..7 row within chunk
    const int sslot  = (lane & 7) ^ subrow;       // pre-swizzled global slot
    const size_t laneoff = (size_t)subrow * DK + sslot * 8;

    const unsigned short* gA[4];
    const unsigned short* gB[4];
    unsigned short* lA[4];
    unsigned short* lB[4];
    #pragma unroll
    for (int m = 0; m < 4; ++m) {
        const int c = wave * 4 + m;               // chunk id, rows c*8..c*8+7
        gA[m] = xb + (size_t)(bm * BM + c * 8) * DK + laneoff;
        gB[m] = yb + (size_t)(bn * BN + c * 8) * DK + laneoff;
        lA[m] = &As[c * 512];                     // 512 ushort = 1 KiB
        lB[m] = &Bs[c * 512];
    }

    f32x16 acc[2][2] = {};

    const int l31  = lane & 31;       // MFMA row/col within 32-tile
    const int half = lane >> 5;       // k-half selector
    const int l7   = lane & 7;        // XOR key (== row&7 for all frag rows)

    const int arow0 = (wm + l31) * BK;   // ushort index of A row (ti=0)
    const int brow0 = (wn + l31) * BK;   // ushort index of B row (tj=0)

    #pragma unroll
    for (int kt = 0; kt < DK; kt += BK) {
        #pragma unroll
        for (int m = 0; m < 4; ++m) {
            __builtin_amdgcn_global_load_lds(
                (const __attribute__((address_space(1))) void*)(gA[m] + kt),
                (__attribute__((address_space(3))) void*)lA[m], 16, 0, 0);
            __builtin_amdgcn_global_load_lds(
                (const __attribute__((address_space(1))) void*)(gB[m] + kt),
                (__attribute__((address_space(3))) void*)lB[m], 16, 0, 0);
        }
        __syncthreads();

        // Four K-steps of 16 from this 64-wide tile.
        #pragma unroll
        for (int ks = 0; ks < 4; ++ks) {
            const int slot = ((ks << 1) | half) ^ l7;   // swizzled 16-B slot
            bf16_8 afr[2], bfr[2];
            afr[0] = *(const bf16_8*)&As[arow0 + slot * 8];
            afr[1] = *(const bf16_8*)&As[arow0 + 32 * BK + slot * 8];
            bfr[0] = *(const bf16_8*)&Bs[brow0 + slot * 8];
            bfr[1] = *(const bf16_8*)&Bs[brow0 + 32 * BK + slot * 8];

            #pragma unroll
            for (int ti = 0; ti < 2; ++ti)
                #pragma unroll
                for (int tj = 0; tj < 2; ++tj)
                    acc[ti][tj] = __builtin_amdgcn_mfma_f32_32x32x16_bf16(
                        afr[ti], bfr[tj], acc[ti][tj], 0, 0, 0);
        }
        __syncthreads();
    }

    // --- epilogue. 32x32 C/D layout (verified m74/m101):
    // col = lane&31, row = (reg&3) + 8*(reg>>2) + 4*(lane>>5), reg in [0,16).
    const int nBase = bn * BN + wn + l31;
    const int mWave = bm * BM + wm + half * 4;

    float y2v[2];
    y2v[0] = y2[nBase];
    y2v[1] = y2[nBase + 32];

    #pragma unroll
    for (int ti = 0; ti < 2; ++ti) {
        #pragma unroll
        for (int g = 0; g < 4; ++g) {          // reg>>2
            #pragma unroll
            for (int rr = 0; rr < 4; ++rr) {   // reg&3
                const int m  = mWave + ti * 32 + rr + 8 * g;
                const float xv = x2[m];
                float* orow = out + (size_t)m * NROWS + nBase;
                #pragma unroll
                for (int tj = 0; tj < 2; ++tj) {
                    const float xy = acc[ti][tj][g * 4 + rr];
                    float s = xv + y2v[tj] - 2.0f * xy;
                    s = fmaxf(s, 0.0f);
                    const float e = __expf(-0.5f * s);
                    const float p = xy + 1.0f;
                    orow[tj * 32] = fmaf(0.1f, p * p * p, e);
                }
            }
        }
    }
}

// ---------------------------------------------------------------------------
extern "C" void kernel_launch(void* const* d_in, const int* in_sizes, int n_in,
                              void* d_out, int out_size, void* d_ws, size_t ws_size,
                              hipStream_t stream) {
    const float* x = (const float*)d_in[0];
    const float* y = (const float*)d_in[1];
    float* out = (float*)d_out;

    char* ws = (char*)d_ws;
    unsigned short* xb = (unsigned short*)ws;                                  // 4 MB
    unsigned short* yb = (unsigned short*)(ws + (size_t)NROWS * DK * 2);       // 4 MB
    float* x2 = (float*)(ws + (size_t)2 * NROWS * DK * 2);                     // 32 KB
    float* y2 = x2 + NROWS;                                                    // 32 KB

    prep_kernel<<<NROWS, 64, 0, stream>>>(x, y, xb, yb, x2, y2);

    dim3 grid(NROWS / BM, NROWS / BN);
    gemm_ep_kernel<<<grid, 256, 0, stream>>>(xb, yb, x2, y2, out);
}